// Round 2
// baseline (464.029 us; speedup 1.0000x reference)
//
#include <hip/hip_runtime.h>
#include <hip/hip_bf16.h>

typedef short s8v __attribute__((ext_vector_type(8)));
typedef float f4v __attribute__((ext_vector_type(4)));

__device__ __forceinline__ float bf2f(short u) {
    unsigned int x = ((unsigned int)(unsigned short)u) << 16;
    return __builtin_bit_cast(float, x);
}
__device__ __forceinline__ short f2bf(float f) {
    unsigned int u = __builtin_bit_cast(unsigned int, f);
    unsigned int r = (u + 0x7FFF + ((u >> 16) & 1)) >> 16;
    return (short)r;
}

// ---- fp32 -> bf16 cast (nelem multiple of 8) ----
__global__ void k_cast(const float* __restrict__ in, short* __restrict__ outp, int nelem) {
    int i = (blockIdx.x * 256 + threadIdx.x) * 8;
    if (i >= nelem) return;
    f4v a = *(const f4v*)(in + i);
    f4v b = *(const f4v*)(in + i + 4);
    s8v o;
    #pragma unroll
    for (int j = 0; j < 4; ++j) { o[j] = f2bf(a[j]); o[j + 4] = f2bf(b[j]); }
    *(s8v*)(outp + i) = o;
}

// ---- degree histogram ----
__global__ void k_deg(const int* __restrict__ dst, int e, int* __restrict__ deg) {
    int i = blockIdx.x * 256 + threadIdx.x;
    if (i < e) atomicAdd(&deg[dst[i]], 1);
}

__global__ void k_dinv(const int* __restrict__ deg, float* __restrict__ dinv, int n) {
    int i = blockIdx.x * 256 + threadIdx.x;
    if (i < n) dinv[i] = rsqrtf((float)deg[i] + 1.0f);
}

// ---- single-block exclusive scan ----
__global__ void k_scan(const int* __restrict__ deg, int* __restrict__ coff, int n) {
    __shared__ int wsum[16];
    __shared__ int carry_s;
    int tid = threadIdx.x, lane = tid & 63, w = tid >> 6;
    if (tid == 0) carry_s = 0;
    __syncthreads();
    for (int base = 0; base < n; base += 1024) {
        int i = base + tid;
        int v = (i < n) ? deg[i] : 0;
        int x = v;
        #pragma unroll
        for (int d2 = 1; d2 < 64; d2 <<= 1) {
            int t = __shfl_up(x, d2, 64);
            if (lane >= d2) x += t;
        }
        if (lane == 63) wsum[w] = x;
        __syncthreads();
        if (w == 0 && lane < 16) {
            int s = wsum[lane];
            int xx = s;
            #pragma unroll
            for (int d2 = 1; d2 < 16; d2 <<= 1) {
                int t = __shfl_up(xx, d2, 64);
                if (lane >= d2) xx += t;
            }
            wsum[lane] = xx - s;
        }
        __syncthreads();
        int excl_wave = wsum[w];
        int carry = carry_s;
        if (i < n) coff[i] = carry + excl_wave + x - v;
        __syncthreads();
        if (tid == 1023) carry_s = carry + excl_wave + x;
        __syncthreads();
    }
    if (tid == 0) coff[n] = carry_s;
}

// ---- CSR fill ----
__global__ void k_fill(const int* __restrict__ src, const int* __restrict__ dst, int e,
                       const int* __restrict__ coff, int* __restrict__ cur,
                       int* __restrict__ csrc) {
    int i = blockIdx.x * 256 + threadIdx.x;
    if (i < e) {
        int d = dst[i];
        int p = atomicAdd(&cur[d], 1);
        csrc[coff[d] + p] = src[i];
    }
}

// ---- bf16 MFMA GEMM: C[M,N](bf16) = A[M,K](bf16) @ B[K,N](fp32, rounded) ----
template<int K, int NT, int CT>
__global__ __launch_bounds__(256)
void k_gemm(const short* __restrict__ A, const float* __restrict__ B,
            short* __restrict__ C, int M) {
    constexpr int S = K / 32;
    constexpr int N = NT * 16 * CT;
    const int lane = threadIdx.x & 63;
    const int gw = (blockIdx.x * 256 + threadIdx.x) >> 6;
    const int nw = (gridDim.x * 256) >> 6;
    const int colset = gw % CT;
    const int strip0 = gw / CT;
    const int sstr = nw / CT;
    const int l15 = lane & 15, l4 = lane >> 4;
    const int colbase = colset * (NT * 16);

    s8v bfr[NT][S];
    #pragma unroll
    for (int nt = 0; nt < NT; ++nt) {
        int col = colbase + nt * 16 + l15;
        #pragma unroll
        for (int s = 0; s < S; ++s) {
            s8v t;
            #pragma unroll
            for (int j = 0; j < 8; ++j)
                t[j] = f2bf(B[(s * 32 + l4 * 8 + j) * N + col]);
            bfr[nt][s] = t;
        }
    }

    const int nstrips = M >> 4;
    for (int strip = strip0; strip < nstrips; strip += sstr) {
        const short* arow = A + (size_t)(strip * 16 + l15) * K + l4 * 8;
        s8v afr[S];
        #pragma unroll
        for (int s = 0; s < S; ++s)
            afr[s] = *(const s8v*)(arow + s * 32);
        f4v acc[NT];
        #pragma unroll
        for (int nt = 0; nt < NT; ++nt) acc[nt] = (f4v){0.f, 0.f, 0.f, 0.f};
        #pragma unroll
        for (int s = 0; s < S; ++s)
            #pragma unroll
            for (int nt = 0; nt < NT; ++nt)
                acc[nt] = __builtin_amdgcn_mfma_f32_16x16x32_bf16(afr[s], bfr[nt][s], acc[nt], 0, 0, 0);
        int orow = strip * 16 + l4 * 4;
        #pragma unroll
        for (int nt = 0; nt < NT; ++nt) {
            int col = colbase + nt * 16 + l15;
            #pragma unroll
            for (int r = 0; r < 4; ++r)
                C[(size_t)(orow + r) * N + col] = f2bf(acc[nt][r]);
        }
    }
}

// ---- aggregation: out[v](bf16) = relu?(dinv[v]*sum_e dinv[s]*h[s] + dinv[v]^2*h[v] + b) ----
template<int D, bool RELU>
__global__ void k_agg(const short* __restrict__ h, const int* __restrict__ coff,
                      const int* __restrict__ csrc, const float* __restrict__ dinv,
                      const float* __restrict__ bias, short* __restrict__ out, int n) {
    constexpr int T = D / 8;
    int node = (blockIdx.x * 256 + threadIdx.x) / T;
    if (node >= n) return;
    int c0 = (threadIdx.x & (T - 1)) * 8;
    float acc[8] = {0.f, 0.f, 0.f, 0.f, 0.f, 0.f, 0.f, 0.f};
    int e0 = coff[node], e1 = coff[node + 1];
    for (int e = e0; e < e1; ++e) {
        int s = csrc[e];
        float ds = dinv[s];
        s8v hv = *(const s8v*)(h + (size_t)s * D + c0);
        #pragma unroll
        for (int j = 0; j < 8; ++j) acc[j] = fmaf(ds, bf2f(hv[j]), acc[j]);
    }
    float dv = dinv[node];
    float dv2 = dv * dv;
    s8v hs = *(const s8v*)(h + (size_t)node * D + c0);
    s8v o;
    #pragma unroll
    for (int j = 0; j < 8; ++j) {
        float v = dv * acc[j] + dv2 * bf2f(hs[j]) + bias[c0 + j];
        if (RELU) v = fmaxf(v, 0.f);
        o[j] = f2bf(v);
    }
    *(s8v*)(out + (size_t)node * D + c0) = o;
}

// ---- layer-3 aggregation fused with mean-pool accumulation (D=64, no relu) ----
__global__ void k_agg_pool(const short* __restrict__ h, const int* __restrict__ coff,
                           const int* __restrict__ csrc, const float* __restrict__ dinv,
                           const float* __restrict__ bias, const int* __restrict__ batch,
                           float* __restrict__ psum, float* __restrict__ pcnt, int n) {
    constexpr int D = 64, T = 8;
    int node = (blockIdx.x * 256 + threadIdx.x) / T;
    if (node >= n) return;
    int t = threadIdx.x & (T - 1);
    int c0 = t * 8;
    float acc[8] = {0.f, 0.f, 0.f, 0.f, 0.f, 0.f, 0.f, 0.f};
    int e0 = coff[node], e1 = coff[node + 1];
    for (int e = e0; e < e1; ++e) {
        int s = csrc[e];
        float ds = dinv[s];
        s8v hv = *(const s8v*)(h + (size_t)s * D + c0);
        #pragma unroll
        for (int j = 0; j < 8; ++j) acc[j] = fmaf(ds, bf2f(hv[j]), acc[j]);
    }
    float dv = dinv[node];
    float dv2 = dv * dv;
    s8v hs = *(const s8v*)(h + (size_t)node * D + c0);
    int g = batch[node];
    #pragma unroll
    for (int j = 0; j < 8; ++j) {
        float v = dv * acc[j] + dv2 * bf2f(hs[j]) + bias[c0 + j];
        atomicAdd(&psum[g * 64 + c0 + j], v);
    }
    if (t == 0) atomicAdd(&pcnt[g], 1.0f);
}

// ---- head: mean-pool finalize, logits, sigmoid, BCE loss (fp32 out) ----
__global__ void k_head(const float* __restrict__ psum, const float* __restrict__ pcnt,
                       const float* __restrict__ Wl, const float* __restrict__ bl,
                       const int* __restrict__ y, float* __restrict__ out) {
    __shared__ float red[512];
    int g = threadIdx.x;
    float cnt = fmaxf(pcnt[g], 1.0f);
    float l = bl[0];
    for (int c = 0; c < 64; ++c)
        l += (psum[g * 64 + c] / cnt) * Wl[c];
    float sg = 1.f / (1.f + expf(-l));
    out[g] = sg;
    float t = (float)y[g];
    float li = fmaxf(l, 0.f) - l * t + log1pf(expf(-fabsf(l)));
    red[g] = li;
    __syncthreads();
    for (int s = 256; s > 0; s >>= 1) {
        if (g < s) red[g] += red[g + s];
        __syncthreads();
    }
    if (g == 0) out[512] = red[0] / 512.f;
}

extern "C" void kernel_launch(void* const* d_in, const int* in_sizes, int n_in,
                              void* d_out, int out_size, void* d_ws, size_t ws_size,
                              hipStream_t stream) {
    const float* x   = (const float*)d_in[0];
    const int* ei    = (const int*)d_in[1];
    const int* batch = (const int*)d_in[2];
    const int* y     = (const int*)d_in[3];
    const float* W1  = (const float*)d_in[4];
    const float* b1  = (const float*)d_in[5];
    const float* W2  = (const float*)d_in[6];
    const float* b2  = (const float*)d_in[7];
    const float* W3  = (const float*)d_in[8];
    const float* b3  = (const float*)d_in[9];
    const float* Wl  = (const float*)d_in[10];
    const float* bl  = (const float*)d_in[11];

    const int n = in_sizes[2];        // 50000 nodes
    const int e = in_sizes[1] / 2;    // 800000 edges

    char* ws = (char*)d_ws;
    size_t off = 0;
    auto alloc = [&](size_t bytes) {
        char* p = ws + off;
        off = (off + bytes + 255) & ~(size_t)255;
        return p;
    };
    int*   deg  = (int*)alloc((size_t)n * 4);
    int*   cur  = (int*)alloc((size_t)n * 4);
    int*   coff = (int*)alloc((size_t)(n + 1) * 4);
    int*   csrc = (int*)alloc((size_t)e * 4);
    float* dinv = (float*)alloc((size_t)n * 4);
    short* hA   = (short*)alloc((size_t)n * 256 * 2);
    short* hB   = (short*)alloc((size_t)n * 256 * 2);
    float* psum = (float*)alloc((size_t)512 * 64 * 4);
    float* pcnt = (float*)alloc((size_t)512 * 4);

    hipMemsetAsync(deg, 0, (size_t)n * 4, stream);
    hipMemsetAsync(cur, 0, (size_t)n * 4, stream);
    hipMemsetAsync(psum, 0, (size_t)512 * 64 * 4, stream);
    hipMemsetAsync(pcnt, 0, (size_t)512 * 4, stream);

    const int gb_e = (e + 255) / 256;
    const int gb_n = (n + 255) / 256;
    k_deg<<<gb_e, 256, 0, stream>>>(ei + e, e, deg);
    k_dinv<<<gb_n, 256, 0, stream>>>(deg, dinv, n);
    k_scan<<<1, 1024, 0, stream>>>(deg, coff, n);
    k_fill<<<gb_e, 256, 0, stream>>>(ei, ei + e, e, coff, cur, csrc);

    // cast x (fp32) -> bf16 into hB
    k_cast<<<(n * 128 / 8 + 255) / 256, 256, 0, stream>>>(x, hB, n * 128);

    // layer 1: xbf[n,128] @ W1[128,256] -> hA; agg+relu -> hB
    k_gemm<128, 4, 4><<<512, 256, 0, stream>>>(hB, W1, hA, n);
    k_agg<256, true><<<(n * 32 + 255) / 256, 256, 0, stream>>>(hA, coff, csrc, dinv, b1, hB, n);
    // layer 2: hB[n,256] @ W2[256,128] -> hA; agg+relu -> hB
    k_gemm<256, 2, 4><<<512, 256, 0, stream>>>(hB, W2, hA, n);
    k_agg<128, true><<<(n * 16 + 255) / 256, 256, 0, stream>>>(hA, coff, csrc, dinv, b2, hB, n);
    // layer 3: hB[n,128] @ W3[128,64] -> hA; agg fused with pooling
    k_gemm<128, 4, 1><<<512, 256, 0, stream>>>(hB, W3, hA, n);
    k_agg_pool<<<(n * 8 + 255) / 256, 256, 0, stream>>>(hA, coff, csrc, dinv, b3, batch, psum, pcnt, n);

    k_head<<<1, 512, 0, stream>>>(psum, pcnt, Wl, bl, y, (float*)d_out);
}

// Round 3
// 339.038 us; speedup vs baseline: 1.3687x; 1.3687x over previous
//
#include <hip/hip_runtime.h>
#include <hip/hip_bf16.h>

typedef short s8v __attribute__((ext_vector_type(8)));
typedef float f4v __attribute__((ext_vector_type(4)));

__device__ __forceinline__ float bf2f(short u) {
    unsigned int x = ((unsigned int)(unsigned short)u) << 16;
    return __builtin_bit_cast(float, x);
}
__device__ __forceinline__ short f2bf(float f) {
    unsigned int u = __builtin_bit_cast(unsigned int, f);
    unsigned int r = (u + 0x7FFF + ((u >> 16) & 1)) >> 16;
    return (short)r;
}

// ---- fp32 -> bf16 cast ----
__global__ void k_cast(const float* __restrict__ in, short* __restrict__ outp, int nelem) {
    int i = (blockIdx.x * 256 + threadIdx.x) * 8;
    if (i >= nelem) return;
    f4v a = *(const f4v*)(in + i);
    f4v b = *(const f4v*)(in + i + 4);
    s8v o;
    #pragma unroll
    for (int j = 0; j < 4; ++j) { o[j] = f2bf(a[j]); o[j + 4] = f2bf(b[j]); }
    *(s8v*)(outp + i) = o;
}

// ---- degree histogram ----
__global__ void k_deg(const int* __restrict__ dst, int e, int* __restrict__ deg) {
    int i = blockIdx.x * 256 + threadIdx.x;
    if (i < e) atomicAdd(&deg[dst[i]], 1);
}

__global__ void k_dinv(const int* __restrict__ deg, float* __restrict__ dinv, int n) {
    int i = blockIdx.x * 256 + threadIdx.x;
    if (i < n) dinv[i] = rsqrtf((float)deg[i] + 1.0f);
}

// ---- single-block exclusive scan ----
__global__ void k_scan(const int* __restrict__ deg, int* __restrict__ coff, int n) {
    __shared__ int wsum[16];
    __shared__ int carry_s;
    int tid = threadIdx.x, lane = tid & 63, w = tid >> 6;
    if (tid == 0) carry_s = 0;
    __syncthreads();
    for (int base = 0; base < n; base += 1024) {
        int i = base + tid;
        int v = (i < n) ? deg[i] : 0;
        int x = v;
        #pragma unroll
        for (int d2 = 1; d2 < 64; d2 <<= 1) {
            int t = __shfl_up(x, d2, 64);
            if (lane >= d2) x += t;
        }
        if (lane == 63) wsum[w] = x;
        __syncthreads();
        if (w == 0 && lane < 16) {
            int s = wsum[lane];
            int xx = s;
            #pragma unroll
            for (int d2 = 1; d2 < 16; d2 <<= 1) {
                int t = __shfl_up(xx, d2, 64);
                if (lane >= d2) xx += t;
            }
            wsum[lane] = xx - s;
        }
        __syncthreads();
        int excl_wave = wsum[w];
        int carry = carry_s;
        if (i < n) coff[i] = carry + excl_wave + x - v;
        __syncthreads();
        if (tid == 1023) carry_s = carry + excl_wave + x;
        __syncthreads();
    }
    if (tid == 0) coff[n] = carry_s;
}

// ---- CSR fill ----
__global__ void k_fill(const int* __restrict__ src, const int* __restrict__ dst, int e,
                       const int* __restrict__ coff, int* __restrict__ cur,
                       int* __restrict__ csrc) {
    int i = blockIdx.x * 256 + threadIdx.x;
    if (i < e) {
        int d = dst[i];
        int p = atomicAdd(&cur[d], 1);
        csrc[coff[d] + p] = src[i];
    }
}

// ---- bf16 MFMA GEMM: C[M,N](bf16) = A[M,K](bf16) @ B[K,N](fp32) [+bias][relu] ----
template<int K, int NT, int CT, bool BIAS, bool RELU>
__global__ __launch_bounds__(256)
void k_gemm(const short* __restrict__ A, const float* __restrict__ B,
            const float* __restrict__ bias, short* __restrict__ C, int M) {
    constexpr int S = K / 32;
    constexpr int N = NT * 16 * CT;
    const int lane = threadIdx.x & 63;
    const int gw = (blockIdx.x * 256 + threadIdx.x) >> 6;
    const int nw = (gridDim.x * 256) >> 6;
    const int colset = gw % CT;
    const int strip0 = gw / CT;
    const int sstr = nw / CT;
    const int l15 = lane & 15, l4 = lane >> 4;
    const int colbase = colset * (NT * 16);

    s8v bfr[NT][S];
    float bcol[NT];
    #pragma unroll
    for (int nt = 0; nt < NT; ++nt) {
        int col = colbase + nt * 16 + l15;
        if (BIAS) bcol[nt] = bias[col];
        #pragma unroll
        for (int s = 0; s < S; ++s) {
            s8v t;
            #pragma unroll
            for (int j = 0; j < 8; ++j)
                t[j] = f2bf(B[(s * 32 + l4 * 8 + j) * N + col]);
            bfr[nt][s] = t;
        }
    }

    const int nstrips = M >> 4;
    for (int strip = strip0; strip < nstrips; strip += sstr) {
        const short* arow = A + (size_t)(strip * 16 + l15) * K + l4 * 8;
        s8v afr[S];
        #pragma unroll
        for (int s = 0; s < S; ++s)
            afr[s] = *(const s8v*)(arow + s * 32);
        f4v acc[NT];
        #pragma unroll
        for (int nt = 0; nt < NT; ++nt) acc[nt] = (f4v){0.f, 0.f, 0.f, 0.f};
        #pragma unroll
        for (int s = 0; s < S; ++s)
            #pragma unroll
            for (int nt = 0; nt < NT; ++nt)
                acc[nt] = __builtin_amdgcn_mfma_f32_16x16x32_bf16(afr[s], bfr[nt][s], acc[nt], 0, 0, 0);
        int orow = strip * 16 + l4 * 4;
        #pragma unroll
        for (int nt = 0; nt < NT; ++nt) {
            int col = colbase + nt * 16 + l15;
            #pragma unroll
            for (int r = 0; r < 4; ++r) {
                float v = acc[nt][r];
                if (BIAS) v += bcol[nt];
                if (RELU) v = fmaxf(v, 0.f);
                C[(size_t)(orow + r) * N + col] = f2bf(v);
            }
        }
    }
}

// ---- aggregation: out[v] = relu?(dinv[v]*sum_e dinv[s]*h[s] + dinv[v]^2*h[v] + b) ----
template<int D, bool RELU, bool F32OUT>
__global__ void k_agg(const short* __restrict__ h, const int* __restrict__ coff,
                      const int* __restrict__ csrc, const float* __restrict__ dinv,
                      const float* __restrict__ bias, void* __restrict__ outp, int n) {
    constexpr int T = D / 8;
    int node = (blockIdx.x * 256 + threadIdx.x) / T;
    if (node >= n) return;
    int c0 = (threadIdx.x & (T - 1)) * 8;
    float acc[8] = {0.f, 0.f, 0.f, 0.f, 0.f, 0.f, 0.f, 0.f};
    int e0 = coff[node], e1 = coff[node + 1];
    for (int e = e0; e < e1; ++e) {
        int s = csrc[e];
        float ds = dinv[s];
        s8v hv = *(const s8v*)(h + (size_t)s * D + c0);
        #pragma unroll
        for (int j = 0; j < 8; ++j) acc[j] = fmaf(ds, bf2f(hv[j]), acc[j]);
    }
    float dv = dinv[node];
    float dv2 = dv * dv;
    s8v hs = *(const s8v*)(h + (size_t)node * D + c0);
    float v[8];
    #pragma unroll
    for (int j = 0; j < 8; ++j) {
        float b = bias ? bias[c0 + j] : 0.f;
        v[j] = dv * acc[j] + dv2 * bf2f(hs[j]) + b;
        if (RELU) v[j] = fmaxf(v[j], 0.f);
    }
    if (F32OUT) {
        float* out = (float*)outp;
        f4v a = {v[0], v[1], v[2], v[3]}, b2 = {v[4], v[5], v[6], v[7]};
        *(f4v*)(out + (size_t)node * D + c0) = a;
        *(f4v*)(out + (size_t)node * D + c0 + 4) = b2;
    } else {
        short* out = (short*)outp;
        s8v o;
        #pragma unroll
        for (int j = 0; j < 8; ++j) o[j] = f2bf(v[j]);
        *(s8v*)(out + (size_t)node * D + c0) = o;
    }
}

// ---- graph start offsets via binary search on sorted batch ----
__global__ void k_bounds(const int* __restrict__ batch, int n, int ngr,
                         int* __restrict__ gstart) {
    int g = blockIdx.x * 256 + threadIdx.x;
    if (g > ngr) return;
    if (g == ngr) { gstart[g] = n; return; }
    int lo = 0, hi = n;
    while (lo < hi) { int mid = (lo + hi) >> 1; if (batch[mid] < g) lo = mid + 1; else hi = mid; }
    gstart[g] = lo;
}

// ---- segmented mean pool: pooled[g][j] = mean over node range ----
__global__ void k_pool(const float* __restrict__ h, const int* __restrict__ gstart,
                       float* __restrict__ pooled) {
    int g = blockIdx.x;
    int j = threadIdx.x;  // 64
    int s = gstart[g], e = gstart[g + 1];
    float acc = 0.f;
    for (int i = s; i < e; ++i) acc += h[(size_t)i * 64 + j];
    float cnt = fmaxf((float)(e - s), 1.0f);
    pooled[g * 64 + j] = acc / cnt;
}

// ---- head: logits, sigmoid, BCE loss ----
__global__ void k_head(const float* __restrict__ pooled,
                       const float* __restrict__ Wl, const float* __restrict__ bl,
                       const int* __restrict__ y, float* __restrict__ out) {
    __shared__ float red[512];
    int g = threadIdx.x;
    float l = bl[0];
    for (int c = 0; c < 64; ++c)
        l += pooled[g * 64 + c] * Wl[c];
    float sg = 1.f / (1.f + expf(-l));
    out[g] = sg;
    float t = (float)y[g];
    float li = fmaxf(l, 0.f) - l * t + log1pf(expf(-fabsf(l)));
    red[g] = li;
    __syncthreads();
    for (int s = 256; s > 0; s >>= 1) {
        if (g < s) red[g] += red[g + s];
        __syncthreads();
    }
    if (g == 0) out[512] = red[0] / 512.f;
}

extern "C" void kernel_launch(void* const* d_in, const int* in_sizes, int n_in,
                              void* d_out, int out_size, void* d_ws, size_t ws_size,
                              hipStream_t stream) {
    const float* x   = (const float*)d_in[0];
    const int* ei    = (const int*)d_in[1];
    const int* batch = (const int*)d_in[2];
    const int* y     = (const int*)d_in[3];
    const float* W1  = (const float*)d_in[4];
    const float* b1  = (const float*)d_in[5];
    const float* W2  = (const float*)d_in[6];
    const float* b2  = (const float*)d_in[7];
    const float* W3  = (const float*)d_in[8];
    const float* b3  = (const float*)d_in[9];
    const float* Wl  = (const float*)d_in[10];
    const float* bl  = (const float*)d_in[11];

    const int n = in_sizes[2];        // 50000 nodes
    const int e = in_sizes[1] / 2;    // 800000 edges
    const int ngr = 512;

    char* ws = (char*)d_ws;
    size_t off = 0;
    auto alloc = [&](size_t bytes) {
        char* p = ws + off;
        off = (off + bytes + 255) & ~(size_t)255;
        return p;
    };
    int*   deg    = (int*)alloc((size_t)n * 4);
    int*   cur    = (int*)alloc((size_t)n * 4);
    int*   coff   = (int*)alloc((size_t)(n + 1) * 4);
    int*   csrc   = (int*)alloc((size_t)e * 4);
    float* dinv   = (float*)alloc((size_t)n * 4);
    short* hA     = (short*)alloc((size_t)n * 256 * 2);
    short* hB     = (short*)alloc((size_t)n * 256 * 2);
    float* h3f    = (float*)alloc((size_t)n * 64 * 4);
    int*   gstart = (int*)alloc((size_t)(ngr + 1) * 4);
    float* pooled = (float*)alloc((size_t)ngr * 64 * 4);

    hipMemsetAsync(deg, 0, (size_t)n * 4, stream);
    hipMemsetAsync(cur, 0, (size_t)n * 4, stream);

    const int gb_e = (e + 255) / 256;
    const int gb_n = (n + 255) / 256;
    k_deg<<<gb_e, 256, 0, stream>>>(ei + e, e, deg);
    k_dinv<<<gb_n, 256, 0, stream>>>(deg, dinv, n);
    k_scan<<<1, 1024, 0, stream>>>(deg, coff, n);
    k_fill<<<gb_e, 256, 0, stream>>>(ei, ei + e, e, coff, cur, csrc);
    k_bounds<<<3, 256, 0, stream>>>(batch, n, ngr, gstart);

    // cast x (fp32) -> bf16 into hB
    k_cast<<<(n * 128 / 8 + 255) / 256, 256, 0, stream>>>(x, hB, n * 128);

    // layer 1 (reassociated): t1 = agg(xb) [n,128]; h1 = relu(t1@W1 + b1) [n,256]
    k_agg<128, false, false><<<(n * 16 + 255) / 256, 256, 0, stream>>>(hB, coff, csrc, dinv, nullptr, hA, n);
    k_gemm<128, 4, 4, true, true><<<512, 256, 0, stream>>>(hA, W1, b1, hB, n);
    // layer 2: g2 = h1@W2 [n,128]; h2 = relu(agg(g2) + b2)
    k_gemm<256, 2, 4, false, false><<<512, 256, 0, stream>>>(hB, W2, nullptr, hA, n);
    k_agg<128, true, false><<<(n * 16 + 255) / 256, 256, 0, stream>>>(hA, coff, csrc, dinv, b2, hB, n);
    // layer 3: g3 = h2@W3 [n,64]; t3 = agg(g3) + b3 (fp32)
    k_gemm<128, 4, 1, false, false><<<512, 256, 0, stream>>>(hB, W3, nullptr, hA, n);
    k_agg<64, false, true><<<(n * 8 + 255) / 256, 256, 0, stream>>>(hA, coff, csrc, dinv, b3, h3f, n);

    // mean pool + head
    k_pool<<<ngr, 64, 0, stream>>>(h3f, gstart, pooled);
    k_head<<<1, 512, 0, stream>>>(pooled, Wl, bl, y, (float*)d_out);
}

// Round 4
// 300.232 us; speedup vs baseline: 1.5456x; 1.1293x over previous
//
#include <hip/hip_runtime.h>
#include <hip/hip_bf16.h>

typedef short s8v __attribute__((ext_vector_type(8)));
typedef float f4v __attribute__((ext_vector_type(4)));

__device__ __forceinline__ float bf2f(short u) {
    unsigned int x = ((unsigned int)(unsigned short)u) << 16;
    return __builtin_bit_cast(float, x);
}
__device__ __forceinline__ short f2bf(float f) {
    unsigned int u = __builtin_bit_cast(unsigned int, f);
    unsigned int r = (u + 0x7FFF + ((u >> 16) & 1)) >> 16;
    return (short)r;
}

// ---- cast + row-scale: out[i,:] = bf16(dinv[i] * x[i,:]), D=128 ----
__global__ void k_cast_scale(const float* __restrict__ in, const float* __restrict__ dinv,
                             short* __restrict__ outp, int ngroups) {
    int i = blockIdx.x * 256 + threadIdx.x;  // one thread per 8 elements
    if (i >= ngroups) return;
    int row = i >> 4;  // 128/8 = 16 groups per row
    float dv = dinv[row];
    f4v a = *(const f4v*)(in + (size_t)i * 8);
    f4v b = *(const f4v*)(in + (size_t)i * 8 + 4);
    s8v o;
    #pragma unroll
    for (int j = 0; j < 4; ++j) { o[j] = f2bf(a[j] * dv); o[j + 4] = f2bf(b[j] * dv); }
    *(s8v*)(outp + (size_t)i * 8) = o;
}

// ---- degree histogram ----
__global__ void k_deg(const int* __restrict__ dst, int e, int* __restrict__ deg) {
    int i = blockIdx.x * 256 + threadIdx.x;
    if (i < e) atomicAdd(&deg[dst[i]], 1);
}

__global__ void k_dinv(const int* __restrict__ deg, float* __restrict__ dinv, int n) {
    int i = blockIdx.x * 256 + threadIdx.x;
    if (i < n) dinv[i] = rsqrtf((float)deg[i] + 1.0f);
}

// ---- hierarchical scan: pass1 per-block (1024 elems) partial exclusive ----
__global__ void k_scan1(const int* __restrict__ deg, int* __restrict__ coff,
                        int* __restrict__ bsum, int n) {
    __shared__ int ws[4];
    int b = blockIdx.x, tid = threadIdx.x, lane = tid & 63, w = tid >> 6;
    int i0 = b * 1024 + tid * 4;
    int v[4];
    int s = 0;
    #pragma unroll
    for (int k = 0; k < 4; ++k) { v[k] = (i0 + k < n) ? deg[i0 + k] : 0; s += v[k]; }
    int x = s;
    #pragma unroll
    for (int d = 1; d < 64; d <<= 1) {
        int t2 = __shfl_up(x, d, 64);
        if (lane >= d) x += t2;
    }
    if (lane == 63) ws[w] = x;
    __syncthreads();
    int wo = 0;
    for (int k = 0; k < w; ++k) wo += ws[k];
    int run = wo + x - s;  // exclusive prefix of this thread's group
    #pragma unroll
    for (int k = 0; k < 4; ++k) {
        if (i0 + k < n) coff[i0 + k] = run;
        run += v[k];
    }
    if (tid == 255) bsum[b] = wo + x;  // block total
}

// ---- pass2: exclusive scan of block sums (nb <= 64) ----
__global__ void k_scan2(int* __restrict__ bsum, int nb) {
    int lane = threadIdx.x;
    int v = (lane < nb) ? bsum[lane] : 0;
    int x = v;
    #pragma unroll
    for (int d = 1; d < 64; d <<= 1) {
        int t2 = __shfl_up(x, d, 64);
        if (lane >= d) x += t2;
    }
    if (lane < nb) bsum[lane] = x - v;
}

// ---- pass3: add block offsets; also write cur = coff, coff[n] = e ----
__global__ void k_scan3(int* __restrict__ coff, int* __restrict__ cur,
                        const int* __restrict__ bsum, int n, int e) {
    int i = blockIdx.x * 256 + threadIdx.x;
    if (i < n) {
        int v = coff[i] + bsum[i >> 10];
        coff[i] = v;
        cur[i] = v;
    } else if (i == n) {
        coff[n] = e;
    }
}

// ---- CSR fill (cur pre-initialized to coff) ----
__global__ void k_fill(const int* __restrict__ src, const int* __restrict__ dst, int e,
                       int* __restrict__ cur, int* __restrict__ csrc) {
    int i = blockIdx.x * 256 + threadIdx.x;
    if (i < e) {
        int p = atomicAdd(&cur[dst[i]], 1);
        csrc[p] = src[i];
    }
}

// ---- bf16 MFMA GEMM: C[M,N] = A[M,K] @ B[K,N]; optional bias/relu/dinv-row-scale ----
template<int K, int NT, int CT, bool BIAS, bool RELU, bool DVS>
__global__ __launch_bounds__(256)
void k_gemm(const short* __restrict__ A, const float* __restrict__ B,
            const float* __restrict__ bias, const float* __restrict__ dinv,
            short* __restrict__ C, int M) {
    constexpr int S = K / 32;
    constexpr int N = NT * 16 * CT;
    const int lane = threadIdx.x & 63;
    const int gw = (blockIdx.x * 256 + threadIdx.x) >> 6;
    const int nw = (gridDim.x * 256) >> 6;
    const int colset = gw % CT;
    const int strip0 = gw / CT;
    const int sstr = nw / CT;
    const int l15 = lane & 15, l4 = lane >> 4;
    const int colbase = colset * (NT * 16);

    s8v bfr[NT][S];
    float bcol[NT];
    #pragma unroll
    for (int nt = 0; nt < NT; ++nt) {
        int col = colbase + nt * 16 + l15;
        if (BIAS) bcol[nt] = bias[col];
        #pragma unroll
        for (int s = 0; s < S; ++s) {
            s8v t;
            #pragma unroll
            for (int j = 0; j < 8; ++j)
                t[j] = f2bf(B[(s * 32 + l4 * 8 + j) * N + col]);
            bfr[nt][s] = t;
        }
    }

    const int nstrips = M >> 4;
    for (int strip = strip0; strip < nstrips; strip += sstr) {
        const short* arow = A + (size_t)(strip * 16 + l15) * K + l4 * 8;
        s8v afr[S];
        #pragma unroll
        for (int s = 0; s < S; ++s)
            afr[s] = *(const s8v*)(arow + s * 32);
        f4v acc[NT];
        #pragma unroll
        for (int nt = 0; nt < NT; ++nt) acc[nt] = (f4v){0.f, 0.f, 0.f, 0.f};
        #pragma unroll
        for (int s = 0; s < S; ++s)
            #pragma unroll
            for (int nt = 0; nt < NT; ++nt)
                acc[nt] = __builtin_amdgcn_mfma_f32_16x16x32_bf16(afr[s], bfr[nt][s], acc[nt], 0, 0, 0);
        int orow = strip * 16 + l4 * 4;
        f4v dvr;
        if (DVS) dvr = *(const f4v*)(dinv + orow);
        #pragma unroll
        for (int nt = 0; nt < NT; ++nt) {
            int col = colbase + nt * 16 + l15;
            #pragma unroll
            for (int r = 0; r < 4; ++r) {
                float v = acc[nt][r];
                if (DVS) v *= dvr[r];
                if (BIAS) v += bcol[nt];
                if (RELU) v = fmaxf(v, 0.f);
                C[(size_t)(orow + r) * N + col] = f2bf(v);
            }
        }
    }
}

// ---- aggregation (inputs pre-scaled by dinv[src]):
//      out[v] = post(dinv[v] * (h[v] + sum_{s in N(v)} h[s]) + bias) ----
template<int D, bool RELU, bool F32OUT, bool BIAS>
__global__ __launch_bounds__(256)
void k_agg(const short* __restrict__ h, const int* __restrict__ coff,
           const int* __restrict__ csrc, const float* __restrict__ dinv,
           const float* __restrict__ bias, void* __restrict__ outp, int n) {
    constexpr int T = D / 8;  // lanes per node
    int node = (blockIdx.x * 256 + threadIdx.x) / T;
    if (node >= n) return;
    int t = threadIdx.x & (T - 1);
    int c0 = t * 8;
    // self term (pre-scaled h[v])
    s8v hv = *(const s8v*)(h + (size_t)node * D + c0);
    float acc[8];
    #pragma unroll
    for (int j = 0; j < 8; ++j) acc[j] = bf2f(hv[j]);

    int e0 = coff[node], e1 = coff[node + 1];
    int base = e0;
    for (; base + T <= e1; base += T) {
        int idx = csrc[base + t];  // coalesced: T lanes, T edges
        #pragma unroll
        for (int j = 0; j < T; ++j) {
            int s = __shfl(idx, j, T);
            s8v v = *(const s8v*)(h + (size_t)s * D + c0);
            #pragma unroll
            for (int k = 0; k < 8; ++k) acc[k] += bf2f(v[k]);
        }
    }
    if (base < e1) {
        int m = e1 - base;
        int idx = csrc[base + (t < m ? t : 0)];
        for (int j = 0; j < m; ++j) {
            int s = __shfl(idx, j, T);
            s8v v = *(const s8v*)(h + (size_t)s * D + c0);
            #pragma unroll
            for (int k = 0; k < 8; ++k) acc[k] += bf2f(v[k]);
        }
    }

    float dv = dinv[node];
    float out[8];
    #pragma unroll
    for (int j = 0; j < 8; ++j) {
        float b = BIAS ? bias[c0 + j] : 0.f;
        out[j] = dv * acc[j] + b;
        if (RELU) out[j] = fmaxf(out[j], 0.f);
    }
    if (F32OUT) {
        float* op = (float*)outp;
        f4v a = {out[0], out[1], out[2], out[3]}, b2 = {out[4], out[5], out[6], out[7]};
        *(f4v*)(op + (size_t)node * D + c0) = a;
        *(f4v*)(op + (size_t)node * D + c0 + 4) = b2;
    } else {
        short* op = (short*)outp;
        s8v o;
        #pragma unroll
        for (int j = 0; j < 8; ++j) o[j] = f2bf(out[j]);
        *(s8v*)(op + (size_t)node * D + c0) = o;
    }
}

// ---- graph start offsets via binary search on sorted batch ----
__global__ void k_bounds(const int* __restrict__ batch, int n, int ngr,
                         int* __restrict__ gstart) {
    int g = blockIdx.x * 256 + threadIdx.x;
    if (g > ngr) return;
    if (g == ngr) { gstart[g] = n; return; }
    int lo = 0, hi = n;
    while (lo < hi) { int mid = (lo + hi) >> 1; if (batch[mid] < g) lo = mid + 1; else hi = mid; }
    gstart[g] = lo;
}

// ---- segmented mean pool ----
__global__ void k_pool(const float* __restrict__ h, const int* __restrict__ gstart,
                       float* __restrict__ pooled) {
    int g = blockIdx.x;
    int j = threadIdx.x;  // 64
    int s = gstart[g], e = gstart[g + 1];
    float acc = 0.f;
    for (int i = s; i < e; ++i) acc += h[(size_t)i * 64 + j];
    float cnt = fmaxf((float)(e - s), 1.0f);
    pooled[g * 64 + j] = acc / cnt;
}

// ---- head: logits, sigmoid, BCE loss ----
__global__ void k_head(const float* __restrict__ pooled,
                       const float* __restrict__ Wl, const float* __restrict__ bl,
                       const int* __restrict__ y, float* __restrict__ out) {
    __shared__ float red[512];
    int g = threadIdx.x;
    float l = bl[0];
    for (int c = 0; c < 64; ++c)
        l += pooled[g * 64 + c] * Wl[c];
    float sg = 1.f / (1.f + expf(-l));
    out[g] = sg;
    float t = (float)y[g];
    float li = fmaxf(l, 0.f) - l * t + log1pf(expf(-fabsf(l)));
    red[g] = li;
    __syncthreads();
    for (int s = 256; s > 0; s >>= 1) {
        if (g < s) red[g] += red[g + s];
        __syncthreads();
    }
    if (g == 0) out[512] = red[0] / 512.f;
}

extern "C" void kernel_launch(void* const* d_in, const int* in_sizes, int n_in,
                              void* d_out, int out_size, void* d_ws, size_t ws_size,
                              hipStream_t stream) {
    const float* x   = (const float*)d_in[0];
    const int* ei    = (const int*)d_in[1];
    const int* batch = (const int*)d_in[2];
    const int* y     = (const int*)d_in[3];
    const float* W1  = (const float*)d_in[4];
    const float* b1  = (const float*)d_in[5];
    const float* W2  = (const float*)d_in[6];
    const float* b2  = (const float*)d_in[7];
    const float* W3  = (const float*)d_in[8];
    const float* b3  = (const float*)d_in[9];
    const float* Wl  = (const float*)d_in[10];
    const float* bl  = (const float*)d_in[11];

    const int n = in_sizes[2];        // 50000 nodes
    const int e = in_sizes[1] / 2;    // 800000 edges
    const int ngr = 512;
    const int nb = (n + 1023) / 1024; // scan blocks (49)

    char* ws = (char*)d_ws;
    size_t off = 0;
    auto alloc = [&](size_t bytes) {
        char* p = ws + off;
        off = (off + bytes + 255) & ~(size_t)255;
        return p;
    };
    int*   deg    = (int*)alloc((size_t)n * 4);
    int*   cur    = (int*)alloc((size_t)n * 4);
    int*   coff   = (int*)alloc((size_t)(n + 1) * 4);
    int*   csrc   = (int*)alloc((size_t)e * 4);
    float* dinv   = (float*)alloc((size_t)n * 4);
    int*   bsum   = (int*)alloc((size_t)(nb + 1) * 4);
    short* hA     = (short*)alloc((size_t)n * 256 * 2);
    short* hB     = (short*)alloc((size_t)n * 256 * 2);
    short* hC     = (short*)alloc((size_t)n * 128 * 2);
    float* h3f    = (float*)alloc((size_t)n * 64 * 4);
    int*   gstart = (int*)alloc((size_t)(ngr + 1) * 4);
    float* pooled = (float*)alloc((size_t)ngr * 64 * 4);

    hipMemsetAsync(deg, 0, (size_t)n * 4, stream);

    const int gb_e = (e + 255) / 256;
    const int gb_n = (n + 255) / 256;

    k_deg<<<gb_e, 256, 0, stream>>>(ei + e, e, deg);
    k_dinv<<<gb_n, 256, 0, stream>>>(deg, dinv, n);
    k_scan1<<<nb, 256, 0, stream>>>(deg, coff, bsum, n);
    k_scan2<<<1, 64, 0, stream>>>(bsum, nb);
    k_scan3<<<(n + 256) / 256, 256, 0, stream>>>(coff, cur, bsum, n, e);
    k_fill<<<gb_e, 256, 0, stream>>>(ei, ei + e, e, cur, csrc);
    k_bounds<<<3, 256, 0, stream>>>(batch, n, ngr, gstart);

    // x' = bf16(dinv * x) -> hC
    k_cast_scale<<<(n * 16 + 255) / 256, 256, 0, stream>>>(x, dinv, hC, n * 16);

    // layer 1: t1 = dv*(x'[v]+sum x'[s]) -> hA[128]; h1 = relu(t1@W1+b1) -> hB[256]
    k_agg<128, false, false, false><<<(n * 16 + 255) / 256, 256, 0, stream>>>(hC, coff, csrc, dinv, nullptr, hA, n);
    k_gemm<128, 4, 4, true, true, false><<<256, 256, 0, stream>>>(hA, W1, b1, nullptr, hB, n);
    // layer 2: g2' = dinv*(h1@W2) -> hA[128]; h2 = relu(dv*(sum)+b2) -> hC[128]
    k_gemm<256, 2, 4, false, false, true><<<256, 256, 0, stream>>>(hB, W2, nullptr, dinv, hA, n);
    k_agg<128, true, false, true><<<(n * 16 + 255) / 256, 256, 0, stream>>>(hA, coff, csrc, dinv, b2, hC, n);
    // layer 3: g3' = dinv*(h2@W3) -> hA[64]; t3 = dv*(sum)+b3 -> h3f (fp32)
    k_gemm<128, 4, 1, false, false, true><<<256, 256, 0, stream>>>(hC, W3, nullptr, dinv, hA, n);
    k_agg<64, false, true, true><<<(n * 8 + 255) / 256, 256, 0, stream>>>(hA, coff, csrc, dinv, b3, h3f, n);

    // mean pool + head
    k_pool<<<ngr, 64, 0, stream>>>(h3f, gstart, pooled);
    k_head<<<1, 512, 0, stream>>>(pooled, Wl, bl, y, (float*)d_out);
}

// Round 5
// 264.542 us; speedup vs baseline: 1.7541x; 1.1349x over previous
//
#include <hip/hip_runtime.h>
#include <hip/hip_bf16.h>

typedef short s8v __attribute__((ext_vector_type(8)));
typedef float f4v __attribute__((ext_vector_type(4)));

__device__ __forceinline__ float bf2f(short u) {
    unsigned int x = ((unsigned int)(unsigned short)u) << 16;
    return __builtin_bit_cast(float, x);
}
__device__ __forceinline__ short f2bf(float f) {
    unsigned int u = __builtin_bit_cast(unsigned int, f);
    unsigned int r = (u + 0x7FFF + ((u >> 16) & 1)) >> 16;
    return (short)r;
}

// ---- cast + row-scale: out[i,:] = bf16(dinv[i] * x[i,:]), D=128 ----
__global__ void k_cast_scale(const float* __restrict__ in, const float* __restrict__ dinv,
                             short* __restrict__ outp, int ngroups) {
    int i = blockIdx.x * 256 + threadIdx.x;
    if (i >= ngroups) return;
    int row = i >> 4;
    float dv = dinv[row];
    f4v a = *(const f4v*)(in + (size_t)i * 8);
    f4v b = *(const f4v*)(in + (size_t)i * 8 + 4);
    s8v o;
    #pragma unroll
    for (int j = 0; j < 4; ++j) { o[j] = f2bf(a[j] * dv); o[j + 4] = f2bf(b[j] * dv); }
    *(s8v*)(outp + (size_t)i * 8) = o;
}

// ---- degree histogram (line-padded counters) + per-edge rank ----
__global__ void k_deg_rank(const int* __restrict__ dst, int e,
                           int* __restrict__ degp, int* __restrict__ rank) {
    int i = (blockIdx.x * 256 + threadIdx.x) * 4;
    if (i + 3 < e) {
        int4 d = *(const int4*)(dst + i);
        int4 r;
        r.x = atomicAdd(&degp[d.x << 4], 1);
        r.y = atomicAdd(&degp[d.y << 4], 1);
        r.z = atomicAdd(&degp[d.z << 4], 1);
        r.w = atomicAdd(&degp[d.w << 4], 1);
        *(int4*)(rank + i) = r;
    } else {
        for (int k = i; k < e; ++k)
            rank[k] = atomicAdd(&degp[dst[k] << 4], 1);
    }
}

// ---- hierarchical scan pass1: per-block (1024 elems) partial exclusive ----
__global__ void k_scan1(const int* __restrict__ degp, int* __restrict__ coff,
                        int* __restrict__ bsum, int n) {
    __shared__ int ws[4];
    int b = blockIdx.x, tid = threadIdx.x, lane = tid & 63, w = tid >> 6;
    int i0 = b * 1024 + tid * 4;
    int v[4];
    int s = 0;
    #pragma unroll
    for (int k = 0; k < 4; ++k) { v[k] = (i0 + k < n) ? degp[(i0 + k) << 4] : 0; s += v[k]; }
    int x = s;
    #pragma unroll
    for (int d = 1; d < 64; d <<= 1) {
        int t2 = __shfl_up(x, d, 64);
        if (lane >= d) x += t2;
    }
    if (lane == 63) ws[w] = x;
    __syncthreads();
    int wo = 0;
    for (int k = 0; k < w; ++k) wo += ws[k];
    int run = wo + x - s;
    #pragma unroll
    for (int k = 0; k < 4; ++k) {
        if (i0 + k < n) coff[i0 + k] = run;
        run += v[k];
    }
    if (tid == 255) bsum[b] = wo + x;
}

// ---- pass2: exclusive scan of block sums (nb <= 64) ----
__global__ void k_scan2(int* __restrict__ bsum, int nb) {
    int lane = threadIdx.x;
    int v = (lane < nb) ? bsum[lane] : 0;
    int x = v;
    #pragma unroll
    for (int d = 1; d < 64; d <<= 1) {
        int t2 = __shfl_up(x, d, 64);
        if (lane >= d) x += t2;
    }
    if (lane < nb) bsum[lane] = x - v;
}

// ---- pass3: finalize coff, compute dinv, coff[n] = e ----
__global__ void k_scan3(int* __restrict__ coff, const int* __restrict__ degp,
                        float* __restrict__ dinv, const int* __restrict__ bsum,
                        int n, int e) {
    int i = blockIdx.x * 256 + threadIdx.x;
    if (i < n) {
        coff[i] += bsum[i >> 10];
        dinv[i] = rsqrtf((float)degp[i << 4] + 1.0f);
    } else if (i == n) {
        coff[n] = e;
    }
}

// ---- CSR fill, atomic-free via rank ----
__global__ void k_fill(const int* __restrict__ src, const int* __restrict__ dst,
                       const int* __restrict__ rank, const int* __restrict__ coff,
                       int e, int* __restrict__ csrc) {
    int i = blockIdx.x * 256 + threadIdx.x;
    if (i < e) csrc[coff[dst[i]] + rank[i]] = src[i];
}

// ---- bf16 MFMA GEMM: C[M,N] = A[M,K] @ B[K,N]; optional bias/relu/dinv-row-scale ----
template<int K, int NT, int CT, bool BIAS, bool RELU, bool DVS>
__global__ __launch_bounds__(256)
void k_gemm(const short* __restrict__ A, const float* __restrict__ B,
            const float* __restrict__ bias, const float* __restrict__ dinv,
            short* __restrict__ C, int M) {
    constexpr int S = K / 32;
    constexpr int N = NT * 16 * CT;
    const int lane = threadIdx.x & 63;
    const int gw = (blockIdx.x * 256 + threadIdx.x) >> 6;
    const int nw = (gridDim.x * 256) >> 6;
    const int colset = gw % CT;
    const int strip0 = gw / CT;
    const int sstr = nw / CT;
    const int l15 = lane & 15, l4 = lane >> 4;
    const int colbase = colset * (NT * 16);

    s8v bfr[NT][S];
    float bcol[NT];
    #pragma unroll
    for (int nt = 0; nt < NT; ++nt) {
        int col = colbase + nt * 16 + l15;
        if (BIAS) bcol[nt] = bias[col];
        #pragma unroll
        for (int s = 0; s < S; ++s) {
            s8v t;
            #pragma unroll
            for (int j = 0; j < 8; ++j)
                t[j] = f2bf(B[(s * 32 + l4 * 8 + j) * N + col]);
            bfr[nt][s] = t;
        }
    }

    const int nstrips = M >> 4;
    for (int strip = strip0; strip < nstrips; strip += sstr) {
        const short* arow = A + (size_t)(strip * 16 + l15) * K + l4 * 8;
        s8v afr[S];
        #pragma unroll
        for (int s = 0; s < S; ++s)
            afr[s] = *(const s8v*)(arow + s * 32);
        f4v acc[NT];
        #pragma unroll
        for (int nt = 0; nt < NT; ++nt) acc[nt] = (f4v){0.f, 0.f, 0.f, 0.f};
        #pragma unroll
        for (int s = 0; s < S; ++s)
            #pragma unroll
            for (int nt = 0; nt < NT; ++nt)
                acc[nt] = __builtin_amdgcn_mfma_f32_16x16x32_bf16(afr[s], bfr[nt][s], acc[nt], 0, 0, 0);
        int orow = strip * 16 + l4 * 4;
        f4v dvr;
        if (DVS) dvr = *(const f4v*)(dinv + orow);
        #pragma unroll
        for (int nt = 0; nt < NT; ++nt) {
            int col = colbase + nt * 16 + l15;
            #pragma unroll
            for (int r = 0; r < 4; ++r) {
                float v = acc[nt][r];
                if (DVS) v *= dvr[r];
                if (BIAS) v += bcol[nt];
                if (RELU) v = fmaxf(v, 0.f);
                C[(size_t)(orow + r) * N + col] = f2bf(v);
            }
        }
    }
}

// ---- aggregation (inputs pre-scaled by dinv[src]):
//      out[v] = post(dinv[v] * (h[v] + sum_{s in N(v)} h[s]) + bias) ----
template<int D, bool RELU, bool F32OUT, bool BIAS>
__global__ __launch_bounds__(256)
void k_agg(const short* __restrict__ h, const int* __restrict__ coff,
           const int* __restrict__ csrc, const float* __restrict__ dinv,
           const float* __restrict__ bias, void* __restrict__ outp, int n) {
    constexpr int T = D / 8;  // lanes per node
    int node = (blockIdx.x * 256 + threadIdx.x) / T;
    if (node >= n) return;
    int t = threadIdx.x & (T - 1);
    int c0 = t * 8;
    s8v hv = *(const s8v*)(h + (size_t)node * D + c0);
    float acc[8];
    #pragma unroll
    for (int j = 0; j < 8; ++j) acc[j] = bf2f(hv[j]);

    int e0 = coff[node], e1 = coff[node + 1];
    int nf = (e1 - e0) & ~(T - 1);
    int endf = e0 + nf;
    int base = e0;
    int idx = 0;
    if (nf) idx = csrc[base + t];
    while (base < endf) {
        int cidx = idx;
        base += T;
        if (base < endf) idx = csrc[base + t];  // prefetch next chunk
        #pragma unroll
        for (int j = 0; j < T; ++j) {
            int s = __shfl(cidx, j, T);
            s8v v = *(const s8v*)(h + (size_t)s * D + c0);
            #pragma unroll
            for (int k = 0; k < 8; ++k) acc[k] += bf2f(v[k]);
        }
    }
    int m = e1 - base;
    if (m > 0) {
        int tidx = csrc[base + (t < m ? t : 0)];
        for (int j = 0; j < m; ++j) {
            int s = __shfl(tidx, j, T);
            s8v v = *(const s8v*)(h + (size_t)s * D + c0);
            #pragma unroll
            for (int k = 0; k < 8; ++k) acc[k] += bf2f(v[k]);
        }
    }

    float dv = dinv[node];
    float out[8];
    #pragma unroll
    for (int j = 0; j < 8; ++j) {
        float b = BIAS ? bias[c0 + j] : 0.f;
        out[j] = dv * acc[j] + b;
        if (RELU) out[j] = fmaxf(out[j], 0.f);
    }
    if (F32OUT) {
        float* op = (float*)outp;
        f4v a = {out[0], out[1], out[2], out[3]}, b2 = {out[4], out[5], out[6], out[7]};
        *(f4v*)(op + (size_t)node * D + c0) = a;
        *(f4v*)(op + (size_t)node * D + c0 + 4) = b2;
    } else {
        short* op = (short*)outp;
        s8v o;
        #pragma unroll
        for (int j = 0; j < 8; ++j) o[j] = f2bf(out[j]);
        *(s8v*)(op + (size_t)node * D + c0) = o;
    }
}

// ---- graph start offsets via binary search on sorted batch ----
__global__ void k_bounds(const int* __restrict__ batch, int n, int ngr,
                         int* __restrict__ gstart) {
    int g = blockIdx.x * 256 + threadIdx.x;
    if (g > ngr) return;
    if (g == ngr) { gstart[g] = n; return; }
    int lo = 0, hi = n;
    while (lo < hi) { int mid = (lo + hi) >> 1; if (batch[mid] < g) lo = mid + 1; else hi = mid; }
    gstart[g] = lo;
}

// ---- segmented mean pool ----
__global__ void k_pool(const float* __restrict__ h, const int* __restrict__ gstart,
                       float* __restrict__ pooled) {
    int g = blockIdx.x;
    int j = threadIdx.x;  // 64
    int s = gstart[g], e = gstart[g + 1];
    float acc = 0.f;
    for (int i = s; i < e; ++i) acc += h[(size_t)i * 64 + j];
    float cnt = fmaxf((float)(e - s), 1.0f);
    pooled[g * 64 + j] = acc / cnt;
}

// ---- head: logits, sigmoid, BCE loss ----
__global__ void k_head(const float* __restrict__ pooled,
                       const float* __restrict__ Wl, const float* __restrict__ bl,
                       const int* __restrict__ y, float* __restrict__ out) {
    __shared__ float red[512];
    int g = threadIdx.x;
    float l = bl[0];
    for (int c = 0; c < 64; ++c)
        l += pooled[g * 64 + c] * Wl[c];
    float sg = 1.f / (1.f + expf(-l));
    out[g] = sg;
    float t = (float)y[g];
    float li = fmaxf(l, 0.f) - l * t + log1pf(expf(-fabsf(l)));
    red[g] = li;
    __syncthreads();
    for (int s = 256; s > 0; s >>= 1) {
        if (g < s) red[g] += red[g + s];
        __syncthreads();
    }
    if (g == 0) out[512] = red[0] / 512.f;
}

extern "C" void kernel_launch(void* const* d_in, const int* in_sizes, int n_in,
                              void* d_out, int out_size, void* d_ws, size_t ws_size,
                              hipStream_t stream) {
    const float* x   = (const float*)d_in[0];
    const int* ei    = (const int*)d_in[1];
    const int* batch = (const int*)d_in[2];
    const int* y     = (const int*)d_in[3];
    const float* W1  = (const float*)d_in[4];
    const float* b1  = (const float*)d_in[5];
    const float* W2  = (const float*)d_in[6];
    const float* b2  = (const float*)d_in[7];
    const float* W3  = (const float*)d_in[8];
    const float* b3  = (const float*)d_in[9];
    const float* Wl  = (const float*)d_in[10];
    const float* bl  = (const float*)d_in[11];

    const int n = in_sizes[2];        // 50000 nodes
    const int e = in_sizes[1] / 2;    // 800000 edges
    const int ngr = 512;
    const int nb = (n + 1023) / 1024; // 49 scan blocks

    char* ws = (char*)d_ws;
    size_t off = 0;
    auto alloc = [&](size_t bytes) {
        char* p = ws + off;
        off = (off + bytes + 255) & ~(size_t)255;
        return p;
    };
    int*   coff   = (int*)alloc((size_t)(n + 1) * 4);
    int*   csrc   = (int*)alloc((size_t)e * 4);
    float* dinv   = (float*)alloc((size_t)n * 4);
    int*   bsum   = (int*)alloc((size_t)(nb + 1) * 4);
    short* hA     = (short*)alloc((size_t)n * 256 * 2);
    short* hB     = (short*)alloc((size_t)n * 256 * 2);
    short* hC     = (short*)alloc((size_t)n * 128 * 2);
    float* h3f    = (float*)alloc((size_t)n * 64 * 4);
    int*   gstart = (int*)alloc((size_t)(ngr + 1) * 4);
    float* pooled = (float*)alloc((size_t)ngr * 64 * 4);

    // alias scratch that dies before its host region is first written:
    // rank dies after k_fill; hA first written by agg1 (after fill).   -> rank = hA
    // degp dies after k_scan3; hB first written by gemm1 (after scan3).-> degp = hB
    int* rank = (int*)hA;
    int* degp = (int*)hB;   // n*16 ints = 3.2 MB (one counter per 64B line)

    hipMemsetAsync(degp, 0, (size_t)n * 64, stream);

    const int gb_n = (n + 255) / 256;

    k_deg_rank<<<(e / 4 + 255) / 256, 256, 0, stream>>>(ei + e, e, degp, rank);
    k_scan1<<<nb, 256, 0, stream>>>(degp, coff, bsum, n);
    k_scan2<<<1, 64, 0, stream>>>(bsum, nb);
    k_scan3<<<(n + 256) / 256, 256, 0, stream>>>(coff, degp, dinv, bsum, n, e);
    k_fill<<<(e + 255) / 256, 256, 0, stream>>>(ei, ei + e, rank, coff, e, csrc);
    k_bounds<<<3, 256, 0, stream>>>(batch, n, ngr, gstart);

    // x' = bf16(dinv * x) -> hC
    k_cast_scale<<<(n * 16 + 255) / 256, 256, 0, stream>>>(x, dinv, hC, n * 16);

    // layer 1: t1 = dv*(x'[v]+sum x'[s]) -> hA[128]; h1 = relu(t1@W1+b1) -> hB[256]
    k_agg<128, false, false, false><<<(n * 16 + 255) / 256, 256, 0, stream>>>(hC, coff, csrc, dinv, nullptr, hA, n);
    k_gemm<128, 4, 4, true, true, false><<<256, 256, 0, stream>>>(hA, W1, b1, nullptr, hB, n);
    // layer 2: g2' = dinv*(h1@W2) -> hA[128]; h2 = relu(dv*(sum)+b2) -> hC[128]
    k_gemm<256, 2, 4, false, false, true><<<256, 256, 0, stream>>>(hB, W2, nullptr, dinv, hA, n);
    k_agg<128, true, false, true><<<(n * 16 + 255) / 256, 256, 0, stream>>>(hA, coff, csrc, dinv, b2, hC, n);
    // layer 3: g3' = dinv*(h2@W3) -> hA[64]; t3 = dv*(sum)+b3 -> h3f (fp32)
    k_gemm<128, 4, 1, false, false, true><<<256, 256, 0, stream>>>(hC, W3, nullptr, dinv, hA, n);
    k_agg<64, false, true, true><<<(n * 8 + 255) / 256, 256, 0, stream>>>(hA, coff, csrc, dinv, b3, h3f, n);

    // mean pool + head
    k_pool<<<ngr, 64, 0, stream>>>(h3f, gstart, pooled);
    k_head<<<1, 512, 0, stream>>>(pooled, Wl, bl, y, (float*)d_out);
}